// Round 1
// baseline (43070.987 us; speedup 1.0000x reference)
//
#include <hip/hip_runtime.h>
#include <cstdint>
#include <cstddef>

// Problem constants (fixed by setup_inputs): B=256 batch, n=512 seq/classes,
// H=512 hidden, 3H=1536 gate width.
#define BB 256
#define NN 512
#define HH 512
#define G3 1536

// ---------------- threefry2x32 (JAX-exact, 20 rounds) ----------------
__device__ __forceinline__ uint32_t rotl32(uint32_t v, int r) {
  return (v << r) | (v >> (32 - r));
}

__device__ __forceinline__ void threefry2x32(uint32_t k0, uint32_t k1,
                                             uint32_t x0, uint32_t x1,
                                             uint32_t& o0, uint32_t& o1) {
  uint32_t k2 = k0 ^ k1 ^ 0x1BD11BDAu;
  x0 += k0; x1 += k1;
  // group 0: 13,15,26,6
  x0 += x1; x1 = rotl32(x1, 13); x1 ^= x0;
  x0 += x1; x1 = rotl32(x1, 15); x1 ^= x0;
  x0 += x1; x1 = rotl32(x1, 26); x1 ^= x0;
  x0 += x1; x1 = rotl32(x1, 6);  x1 ^= x0;
  x0 += k1; x1 += k2 + 1u;
  // group 1: 17,29,16,24
  x0 += x1; x1 = rotl32(x1, 17); x1 ^= x0;
  x0 += x1; x1 = rotl32(x1, 29); x1 ^= x0;
  x0 += x1; x1 = rotl32(x1, 16); x1 ^= x0;
  x0 += x1; x1 = rotl32(x1, 24); x1 ^= x0;
  x0 += k2; x1 += k0 + 2u;
  // group 2: 13,15,26,6
  x0 += x1; x1 = rotl32(x1, 13); x1 ^= x0;
  x0 += x1; x1 = rotl32(x1, 15); x1 ^= x0;
  x0 += x1; x1 = rotl32(x1, 26); x1 ^= x0;
  x0 += x1; x1 = rotl32(x1, 6);  x1 ^= x0;
  x0 += k0; x1 += k1 + 3u;
  // group 3: 17,29,16,24
  x0 += x1; x1 = rotl32(x1, 17); x1 ^= x0;
  x0 += x1; x1 = rotl32(x1, 29); x1 ^= x0;
  x0 += x1; x1 = rotl32(x1, 16); x1 ^= x0;
  x0 += x1; x1 = rotl32(x1, 24); x1 ^= x0;
  x0 += k1; x1 += k2 + 4u;
  // group 4: 13,15,26,6
  x0 += x1; x1 = rotl32(x1, 13); x1 ^= x0;
  x0 += x1; x1 = rotl32(x1, 15); x1 ^= x0;
  x0 += x1; x1 = rotl32(x1, 26); x1 ^= x0;
  x0 += x1; x1 = rotl32(x1, 6);  x1 ^= x0;
  x0 += k2; x1 += k0 + 5u;
  o0 = x0; o1 = x1;
}

// ---------------- init kernels ----------------
// h0h1 points at a contiguous [2*B*H] region (h0 then h1).
__global__ __launch_bounds__(256) void init_state_kernel(
    float* __restrict__ h0h1, uint32_t* __restrict__ avail,
    float* __restrict__ lp, int* __restrict__ idx) {
  int i = blockIdx.x * 256 + threadIdx.x;
  if (i < 2 * BB * HH) h0h1[i] = 0.0f;
  if (i < BB * (NN / 32)) avail[i] = 0xFFFFFFFFu;
  if (i < BB) { lp[i] = 0.0f; idx[i] = 0; }
}

// gi0 for t=0 (inp = ones): ones_row[j] = sum_k W_ih0[j,k] + b_ih0[j]
__global__ __launch_bounds__(256) void ones_row_kernel(
    const float* __restrict__ W_ih0, const float* __restrict__ b_ih0,
    float* __restrict__ ones_row) {
  int j = blockIdx.x * 256 + threadIdx.x;
  if (j < G3) {
    const float* row = W_ih0 + (size_t)j * NN;
    float s = 0.0f;
    for (int k = 0; k < NN; ++k) s += row[k];
    ones_row[j] = s + b_ih0[j];
  }
}

// W_ih0T[k][j] = W_ih0[j][k]  ([G3,NN] -> [NN,G3]) so the one-hot gather is a
// coalesced row read.
__global__ __launch_bounds__(256) void transpose_kernel(
    const float* __restrict__ in, float* __restrict__ out) {
  __shared__ float tile[32][33];
  int bx = blockIdx.x;           // over NN (k), 16 tiles
  int by = blockIdx.y;           // over G3 (j), 48 tiles
  int tx = threadIdx.x & 31;
  int ty = threadIdx.x >> 5;     // 0..7
  for (int i = 0; i < 32; i += 8)
    tile[ty + i][tx] = in[(size_t)(by * 32 + ty + i) * NN + bx * 32 + tx];
  __syncthreads();
  for (int i = 0; i < 32; i += 8)
    out[(size_t)(bx * 32 + ty + i) * G3 + by * 32 + tx] = tile[tx][ty + i];
}

// ---------------- tiled fp32 GEMM: C = A @ W^T + bias ----------------
// A [256,K] row-major, W [n,K] row-major, C [256,n].
// BM=BN=32, BK=32; 256 threads; each thread a 2x2 micro-tile.
// blockIdx.z selects operand set (used to batch gh0/gh1 in one launch).
__global__ __launch_bounds__(256) void gemm_bt_kernel(
    const float* __restrict__ A0, const float* __restrict__ W0,
    const float* __restrict__ bias0, float* __restrict__ C0,
    const float* __restrict__ A1, const float* __restrict__ W1,
    const float* __restrict__ bias1, float* __restrict__ C1,
    int n, int k) {
  const float* A = blockIdx.z ? A1 : A0;
  const float* W = blockIdx.z ? W1 : W0;
  const float* bias = blockIdx.z ? bias1 : bias0;
  float* C = blockIdx.z ? C1 : C0;

  __shared__ float As[32][33];
  __shared__ float Ws[32][33];

  int tid = threadIdx.x;
  int m0 = blockIdx.x * 32;
  int n0 = blockIdx.y * 32;
  int ty = tid >> 4;         // 0..15
  int tx = tid & 15;         // 0..15
  int lrow = tid >> 3;       // 0..31
  int lc4 = (tid & 7) * 4;   // 0,4,...,28

  float acc00 = 0.f, acc01 = 0.f, acc10 = 0.f, acc11 = 0.f;

  for (int kk = 0; kk < k; kk += 32) {
    float4 av = *(const float4*)(A + (size_t)(m0 + lrow) * k + kk + lc4);
    As[lrow][lc4 + 0] = av.x; As[lrow][lc4 + 1] = av.y;
    As[lrow][lc4 + 2] = av.z; As[lrow][lc4 + 3] = av.w;
    float4 wv = *(const float4*)(W + (size_t)(n0 + lrow) * k + kk + lc4);
    Ws[lrow][lc4 + 0] = wv.x; Ws[lrow][lc4 + 1] = wv.y;
    Ws[lrow][lc4 + 2] = wv.z; Ws[lrow][lc4 + 3] = wv.w;
    __syncthreads();
#pragma unroll
    for (int k2 = 0; k2 < 32; ++k2) {
      float a0 = As[ty][k2];
      float a1 = As[ty + 16][k2];
      float w0 = Ws[tx][k2];
      float w1 = Ws[tx + 16][k2];
      acc00 += a0 * w0; acc01 += a0 * w1;
      acc10 += a1 * w0; acc11 += a1 * w1;
    }
    __syncthreads();
  }
  float bv0 = bias[n0 + tx];
  float bv1 = bias[n0 + tx + 16];
  C[(size_t)(m0 + ty) * n + n0 + tx] = acc00 + bv0;
  C[(size_t)(m0 + ty) * n + n0 + tx + 16] = acc01 + bv1;
  C[(size_t)(m0 + ty + 16) * n + n0 + tx] = acc10 + bv0;
  C[(size_t)(m0 + ty + 16) * n + n0 + tx + 16] = acc11 + bv1;
}

// ---------------- GRU gate elementwise ----------------
__device__ __forceinline__ float sigmoidf_(float x) {
  return 1.0f / (1.0f + expf(-x));
}

// layer 0: gi via one-hot gather (or ones_row at t=0); gh0 already has b_hh0.
__global__ __launch_bounds__(256) void cell0_kernel(
    const float* __restrict__ gh0, const float* __restrict__ W_ih0T,
    const float* __restrict__ b_ih0, const float* __restrict__ ones_row,
    const int* __restrict__ idx, float* __restrict__ h0, int t) {
  int i = blockIdx.x * 256 + threadIdx.x;  // 0..131071
  int b = i >> 9;
  int h = i & 511;
  float ir, iz, in_;
  if (t == 0) {
    ir = ones_row[h]; iz = ones_row[h + HH]; in_ = ones_row[h + 2 * HH];
  } else {
    const float* wrow = W_ih0T + (size_t)idx[b] * G3;
    ir = wrow[h] + b_ih0[h];
    iz = wrow[h + HH] + b_ih0[h + HH];
    in_ = wrow[h + 2 * HH] + b_ih0[h + 2 * HH];
  }
  const float* gr = gh0 + (size_t)b * G3;
  float hr = gr[h], hz = gr[h + HH], hn = gr[h + 2 * HH];
  float r = sigmoidf_(ir + hr);
  float z = sigmoidf_(iz + hz);
  float ng = tanhf(in_ + r * hn);
  float hold = h0[i];
  h0[i] = (1.0f - z) * ng + z * hold;
}

// layer 1: gi1 (has b_ih1) + gh1 (has b_hh1) -> h1 in place.
__global__ __launch_bounds__(256) void cell1_kernel(
    const float* __restrict__ gi1, const float* __restrict__ gh1,
    float* __restrict__ h1) {
  int i = blockIdx.x * 256 + threadIdx.x;
  int b = i >> 9;
  int h = i & 511;
  const float* gi = gi1 + (size_t)b * G3;
  const float* gh = gh1 + (size_t)b * G3;
  float r = sigmoidf_(gi[h] + gh[h]);
  float z = sigmoidf_(gi[h + HH] + gh[h + HH]);
  float ng = tanhf(gi[h + 2 * HH] + r * gh[h + 2 * HH]);
  float hold = h1[i];
  h1[i] = (1.0f - z) * ng + z * hold;
}

// ---------------- sampler: mask, gumbel-argmax, softmax, lp ----------------
// One block per batch row b; 256 threads, 2 columns each.
__global__ __launch_bounds__(256) void sample_kernel(
    const float* __restrict__ logits, uint32_t* __restrict__ avail,
    float* __restrict__ lp, int* __restrict__ idx,
    float* __restrict__ out_perm, float* __restrict__ out_lp, int t) {
  int b = blockIdx.x;
  int tid = threadIdx.x;

  // step key: split(key(42), 512) -> key_t. counts 0..1023, pairs (j, j+512).
  uint32_t tp = (uint32_t)(t & 255);
  uint32_t a0, a1, b0, b1;
  threefry2x32(0u, 42u, 2u * tp, 2u * tp + 512u, a0, a1);
  threefry2x32(0u, 42u, 2u * tp + 1u, 2u * tp + 1u + 512u, b0, b1);
  uint32_t sk0 = (t < 256) ? a0 : a1;
  uint32_t sk1 = (t < 256) ? b0 : b1;

  __shared__ float rv[256];
  __shared__ int ri[256];
  __shared__ float rm[256];

  uint32_t bl = (uint32_t)(b & 127);
  float best_v = -1.0f / 0.0f;
  int best_i = 0;
  float mymax = -1.0f / 0.0f;
  float ml_[2];

#pragma unroll
  for (int j = 0; j < 2; ++j) {
    int c = tid + j * 256;
    // random_bits(key_t, 32, (256,512)): counts iota(131072), pairs (m, m+65536)
    uint32_t cnt = bl * 512u + (uint32_t)c;
    uint32_t r0, r1;
    threefry2x32(sk0, sk1, cnt, cnt + 65536u, r0, r1);
    uint32_t bits = (b < 128) ? r0 : r1;
    float u = __uint_as_float((bits >> 9) | 0x3f800000u) - 1.0f;
    if (u == 0.0f) u = 1.17549435e-38f;  // uniform minval=tiny
    float g = -logf(-logf(u));
    float l = logits[(size_t)b * NN + c];
    bool av = (avail[b * 16 + (c >> 5)] >> (c & 31)) & 1u;
    float ml = av ? l : -1.0e9f;
    ml_[j] = ml;
    float v = g + ml;
    if (v > best_v || (v == best_v && c < best_i)) { best_v = v; best_i = c; }
    mymax = fmaxf(mymax, ml);
  }

  rv[tid] = best_v; ri[tid] = best_i; rm[tid] = mymax;
  __syncthreads();
  for (int s = 128; s > 0; s >>= 1) {
    if (tid < s) {
      float v2 = rv[tid + s]; int i2 = ri[tid + s];
      if (v2 > rv[tid] || (v2 == rv[tid] && i2 < ri[tid])) {
        rv[tid] = v2; ri[tid] = i2;
      }
      rm[tid] = fmaxf(rm[tid], rm[tid + s]);
    }
    __syncthreads();
  }
  float m = rm[0];
  int sel = ri[0];
  __syncthreads();
  // sum of exp(ml - m); masked rows contribute exp(-1e9 - m) == 0 exactly.
  rm[tid] = expf(ml_[0] - m) + expf(ml_[1] - m);
  __syncthreads();
  for (int s = 128; s > 0; s >>= 1) {
    if (tid < s) rm[tid] += rm[tid + s];
    __syncthreads();
  }
  if (tid == 0) {
    float ssum = rm[0];
    float lsel = logits[(size_t)b * NN + sel];  // winner is always available
    float p = expf(lsel - m) / ssum;
    float lpn = lp[b] + logf(p + 1e-9f);
    lp[b] = lpn;
    out_lp[b] = lpn;  // overwritten each step; final step's value stands
    idx[b] = sel;
    avail[b * 16 + (sel >> 5)] &= ~(1u << (sel & 31));
    out_perm[(size_t)b * NN * NN + (size_t)t * NN + sel] = 1.0f;
  }
}

// ---------------- host ----------------
extern "C" void kernel_launch(void* const* d_in, const int* in_sizes, int n_in,
                              void* d_out, int out_size, void* d_ws,
                              size_t ws_size, hipStream_t stream) {
  (void)in_sizes; (void)n_in; (void)ws_size;
  const float* W_ih0 = (const float*)d_in[1];
  const float* W_hh0 = (const float*)d_in[2];
  const float* b_ih0 = (const float*)d_in[3];
  const float* b_hh0 = (const float*)d_in[4];
  const float* W_ih1 = (const float*)d_in[5];
  const float* W_hh1 = (const float*)d_in[6];
  const float* b_ih1 = (const float*)d_in[7];
  const float* b_hh1 = (const float*)d_in[8];
  const float* W_out = (const float*)d_in[9];
  const float* b_out = (const float*)d_in[10];

  // workspace layout (floats); ~9.5 MB total
  float* ws = (float*)d_ws;
  float* h0 = ws;                         // 131072  (h0,h1 contiguous for init)
  float* h1 = ws + 131072;                // 131072
  float* gh0 = ws + 262144;               // 393216
  float* gh1 = ws + 655360;               // 393216
  float* gi1 = ws + 1048576;              // 393216
  float* logits = ws + 1441792;           // 131072
  float* W_ih0T = ws + 1572864;           // 786432
  float* ones_row = ws + 2359296;         // 1536
  float* lp = ws + 2360832;               // 256
  uint32_t* avail = (uint32_t*)(ws + 2361088);  // 4096 u32
  int* idx = (int*)(ws + 2365184);        // 256

  float* out = (float*)d_out;
  float* out_lp = out + (size_t)BB * NN * NN;

  hipMemsetAsync(d_out, 0, (size_t)out_size * sizeof(float), stream);
  init_state_kernel<<<1024, 256, 0, stream>>>(h0, avail, lp, idx);
  ones_row_kernel<<<6, 256, 0, stream>>>(W_ih0, b_ih0, ones_row);
  transpose_kernel<<<dim3(16, 48), 256, 0, stream>>>(W_ih0, W_ih0T);

  for (int t = 0; t < NN; ++t) {
    // gh0 = h0 @ W_hh0^T + b_hh0 ; gh1 = h1 @ W_hh1^T + b_hh1 (batched, z=2)
    gemm_bt_kernel<<<dim3(8, 48, 2), 256, 0, stream>>>(
        h0, W_hh0, b_hh0, gh0, h1, W_hh1, b_hh1, gh1, G3, HH);
    // h0 <- GRUcell(one-hot(idx) or ones, h0)
    cell0_kernel<<<512, 256, 0, stream>>>(gh0, W_ih0T, b_ih0, ones_row, idx,
                                          h0, t);
    // gi1 = h0n @ W_ih1^T + b_ih1
    gemm_bt_kernel<<<dim3(8, 48, 1), 256, 0, stream>>>(
        h0, W_ih1, b_ih1, gi1, h0, W_ih1, b_ih1, gi1, G3, HH);
    // h1 <- GRUcell gates(gi1, gh1)
    cell1_kernel<<<512, 256, 0, stream>>>(gi1, gh1, h1);
    // logits = h1n @ W_out^T + b_out
    gemm_bt_kernel<<<dim3(8, 16, 1), 256, 0, stream>>>(
        h1, W_out, b_out, logits, h1, W_out, b_out, logits, NN, HH);
    // mask, gumbel-argmax (threefry-exact), softmax, lp, perm row, avail
    sample_kernel<<<256, 256, 0, stream>>>(logits, avail, lp, idx, out, out_lp,
                                           t);
  }
}

// Round 2
// 29536.343 us; speedup vs baseline: 1.4582x; 1.4582x over previous
//
#include <hip/hip_runtime.h>
#include <cstdint>
#include <cstddef>

// B=256 batch, n=512 classes/steps, H=512 hidden, 3H=1536.
#define BB 256
#define NN 512
#define HH 512
#define G3 1536

typedef short bf16x8 __attribute__((ext_vector_type(8)));
typedef float f32x4 __attribute__((ext_vector_type(4)));

// ---------------- bf16 hi/lo split helpers ----------------
__device__ __forceinline__ unsigned short bf16_rne(float f) {
  uint32_t u = __float_as_uint(f);
  uint32_t r = u + 0x7FFFu + ((u >> 16) & 1u);
  return (unsigned short)(r >> 16);
}
__device__ __forceinline__ float bf16_to_f(unsigned short h) {
  return __uint_as_float(((uint32_t)h) << 16);
}

// Load 16 consecutive floats from global, split to bf16 hi/lo, store to LDS.
__device__ __forceinline__ void stage16(const float* __restrict__ g,
                                        short* __restrict__ hi,
                                        short* __restrict__ lo) {
  float v[16];
#pragma unroll
  for (int i = 0; i < 4; ++i)
    *(float4*)&v[i * 4] = *(const float4*)(g + i * 4);
  short hb[16], lb[16];
#pragma unroll
  for (int i = 0; i < 16; ++i) {
    unsigned short h = bf16_rne(v[i]);
    float hf = bf16_to_f(h);
    unsigned short l = bf16_rne(v[i] - hf);
    hb[i] = (short)h;
    lb[i] = (short)l;
  }
  *(bf16x8*)hi = *(const bf16x8*)hb;
  *(bf16x8*)(hi + 8) = *(const bf16x8*)(hb + 8);
  *(bf16x8*)lo = *(const bf16x8*)lb;
  *(bf16x8*)(lo + 8) = *(const bf16x8*)(lb + 8);
}

// ---------------- threefry2x32 (JAX-exact, 20 rounds) ----------------
__device__ __forceinline__ uint32_t rotl32(uint32_t v, int r) {
  return (v << r) | (v >> (32 - r));
}

__device__ __forceinline__ void threefry2x32(uint32_t k0, uint32_t k1,
                                             uint32_t x0, uint32_t x1,
                                             uint32_t& o0, uint32_t& o1) {
  uint32_t k2 = k0 ^ k1 ^ 0x1BD11BDAu;
  x0 += k0; x1 += k1;
  x0 += x1; x1 = rotl32(x1, 13); x1 ^= x0;
  x0 += x1; x1 = rotl32(x1, 15); x1 ^= x0;
  x0 += x1; x1 = rotl32(x1, 26); x1 ^= x0;
  x0 += x1; x1 = rotl32(x1, 6);  x1 ^= x0;
  x0 += k1; x1 += k2 + 1u;
  x0 += x1; x1 = rotl32(x1, 17); x1 ^= x0;
  x0 += x1; x1 = rotl32(x1, 29); x1 ^= x0;
  x0 += x1; x1 = rotl32(x1, 16); x1 ^= x0;
  x0 += x1; x1 = rotl32(x1, 24); x1 ^= x0;
  x0 += k2; x1 += k0 + 2u;
  x0 += x1; x1 = rotl32(x1, 13); x1 ^= x0;
  x0 += x1; x1 = rotl32(x1, 15); x1 ^= x0;
  x0 += x1; x1 = rotl32(x1, 26); x1 ^= x0;
  x0 += x1; x1 = rotl32(x1, 6);  x1 ^= x0;
  x0 += k0; x1 += k1 + 3u;
  x0 += x1; x1 = rotl32(x1, 17); x1 ^= x0;
  x0 += x1; x1 = rotl32(x1, 29); x1 ^= x0;
  x0 += x1; x1 = rotl32(x1, 16); x1 ^= x0;
  x0 += x1; x1 = rotl32(x1, 24); x1 ^= x0;
  x0 += k1; x1 += k2 + 4u;
  x0 += x1; x1 = rotl32(x1, 13); x1 ^= x0;
  x0 += x1; x1 = rotl32(x1, 15); x1 ^= x0;
  x0 += x1; x1 = rotl32(x1, 26); x1 ^= x0;
  x0 += x1; x1 = rotl32(x1, 6);  x1 ^= x0;
  x0 += k2; x1 += k0 + 5u;
  o0 = x0; o1 = x1;
}

// ---------------- init kernels ----------------
// hbase: 4 contiguous h buffers (h0A,h0B,h1A,h1B) = 4*B*H floats.
__global__ __launch_bounds__(256) void init_state_kernel(
    float* __restrict__ hbase, uint32_t* __restrict__ avail,
    float* __restrict__ lp, int* __restrict__ idx) {
  int i = blockIdx.x * 256 + threadIdx.x;
  if (i < 4 * BB * HH) hbase[i] = 0.0f;
  if (i < BB * (NN / 32)) avail[i] = 0xFFFFFFFFu;
  if (i < BB) { lp[i] = 0.0f; idx[i] = 0; }
}

// ones_row[j] = sum_k W_ih0[j,k] + b_ih0[j]  (gi0 at t=0, inp = ones)
__global__ __launch_bounds__(256) void ones_row_kernel(
    const float* __restrict__ W_ih0, const float* __restrict__ b_ih0,
    float* __restrict__ ones_row) {
  int j = blockIdx.x * 256 + threadIdx.x;
  if (j < G3) {
    const float* row = W_ih0 + (size_t)j * NN;
    float s = 0.0f;
    for (int k = 0; k < NN; ++k) s += row[k];
    ones_row[j] = s + b_ih0[j];
  }
}

// W_ih0T[k][j] = W_ih0[j][k]  ([G3,NN] -> [NN,G3]) for one-hot row gather.
__global__ __launch_bounds__(256) void transpose_kernel(
    const float* __restrict__ in, float* __restrict__ out) {
  __shared__ float tile[32][33];
  int bx = blockIdx.x;  // over NN, 16 tiles
  int by = blockIdx.y;  // over G3, 48 tiles
  int tx = threadIdx.x & 31;
  int ty = threadIdx.x >> 5;  // 0..7
  for (int i = 0; i < 32; i += 8)
    tile[ty + i][tx] = in[(size_t)(by * 32 + ty + i) * NN + bx * 32 + tx];
  __syncthreads();
  for (int i = 0; i < 32; i += 8)
    out[(size_t)(bx * 32 + ty + i) * G3 + by * 32 + tx] = tile[tx][ty + i];
}

// ---------------- fused GRU step GEMM (MFMA bf16 hi/lo split) ----------------
// C[b][c] = sum_k A[b][k] * W[c][k], fp32-precision via 3-product bf16 split.
// Block: 64 b-rows x one 16-wide h-block x 3 gates (48 W rows).
// mode 0: A=h0r, W=W_hh0, epilogue cell0 -> h0w
// mode 1: A=h1r, W=W_hh1, epilogue store gh1 (gate-interleaved [b][hb*48+g*16+i])
// mode 2: A=h0w, W=W_ih1, epilogue cell1 (uses gh1, h1r) -> h1w
__global__ __launch_bounds__(256) void fused_step_kernel(
    int base_mode, int t,
    const float* __restrict__ h0r, float* __restrict__ h0w,
    const float* __restrict__ h1r, float* __restrict__ h1w,
    float* __restrict__ gh1,
    const float* __restrict__ W_hh0, const float* __restrict__ W_hh1,
    const float* __restrict__ W_ih1,
    const float* __restrict__ b_hh0, const float* __restrict__ b_hh1,
    const float* __restrict__ b_ih1,
    const float* __restrict__ W_ih0T, const float* __restrict__ b_ih0,
    const float* __restrict__ ones_row, const int* __restrict__ idx) {
  const int mode = base_mode + blockIdx.z;
  const float* A;
  const float* W;
  if (mode == 0)      { A = h0r; W = W_hh0; }
  else if (mode == 1) { A = h1r; W = W_hh1; }
  else                { A = h0w; W = W_ih1; }

  // LDS tiles: BK=64, row stride 72 shorts (144 B: 16B-aligned, 2-way banks).
  __shared__ short Ahi[64 * 72], Alo[64 * 72];
  __shared__ short Whi[48 * 72], Wlo[48 * 72];

  const int tid = threadIdx.x;
  const int m0 = blockIdx.x * 64;  // b-tile
  const int hb = blockIdx.y;       // h-block 0..31

  const int sr = tid >> 2;         // staging row 0..63
  const int sc = (tid & 3) << 4;   // staging col 0,16,32,48

  const int w  = tid >> 6;         // wave 0..3 -> m-group
  const int ln = tid & 63;
  const int ci = ln & 15;          // frag row/col index
  const int qu = ln >> 4;          // quad

  f32x4 acc[3];
  acc[0] = (f32x4){0.f, 0.f, 0.f, 0.f};
  acc[1] = acc[0];
  acc[2] = acc[0];

  const float* Abase = A + (size_t)(m0 + sr) * HH + sc;
  const float* Wbase = nullptr;
  if (sr < 48) {
    int g = sr >> 4, i = sr & 15;
    Wbase = W + (size_t)(g * HH + hb * 16 + i) * HH + sc;
  }

  for (int kk = 0; kk < HH; kk += 64) {
    stage16(Abase + kk, &Ahi[sr * 72 + sc], &Alo[sr * 72 + sc]);
    if (sr < 48) stage16(Wbase + kk, &Whi[sr * 72 + sc], &Wlo[sr * 72 + sc]);
    __syncthreads();
#pragma unroll
    for (int s = 0; s < 2; ++s) {
      const int ko = s * 32 + qu * 8;
      bf16x8 ah = *(const bf16x8*)&Ahi[(w * 16 + ci) * 72 + ko];
      bf16x8 al = *(const bf16x8*)&Alo[(w * 16 + ci) * 72 + ko];
#pragma unroll
      for (int g = 0; g < 3; ++g) {
        bf16x8 bh = *(const bf16x8*)&Whi[(g * 16 + ci) * 72 + ko];
        bf16x8 bl = *(const bf16x8*)&Wlo[(g * 16 + ci) * 72 + ko];
        acc[g] = __builtin_amdgcn_mfma_f32_16x16x32_bf16(ah, bh, acc[g], 0, 0, 0);
        acc[g] = __builtin_amdgcn_mfma_f32_16x16x32_bf16(ah, bl, acc[g], 0, 0, 0);
        acc[g] = __builtin_amdgcn_mfma_f32_16x16x32_bf16(al, bh, acc[g], 0, 0, 0);
      }
    }
    __syncthreads();
  }

  // epilogue: lane holds, for col h=hb*16+ci, rows b=brow0..brow0+3, all gates.
  const int h = hb * 16 + ci;
  const int brow0 = m0 + w * 16 + qu * 4;

  if (mode == 1) {
    float bz0 = b_hh1[h], bz1 = b_hh1[HH + h], bz2 = b_hh1[2 * HH + h];
#pragma unroll
    for (int r = 0; r < 4; ++r) {
      int b = brow0 + r;
      float* dst = gh1 + (size_t)b * G3 + hb * 48 + ci;
      dst[0]  = acc[0][r] + bz0;
      dst[16] = acc[1][r] + bz1;
      dst[32] = acc[2][r] + bz2;
    }
  } else if (mode == 0) {
    float br = b_hh0[h], bz = b_hh0[HH + h], bn = b_hh0[2 * HH + h];
    float o0 = ones_row[h], o1 = ones_row[HH + h], o2 = ones_row[2 * HH + h];
    float bi0 = b_ih0[h], bi1 = b_ih0[HH + h], bi2 = b_ih0[2 * HH + h];
#pragma unroll
    for (int r = 0; r < 4; ++r) {
      int b = brow0 + r;
      float ir, iz, in_;
      if (t == 0) {
        ir = o0; iz = o1; in_ = o2;
      } else {
        const float* wr_ = W_ih0T + (size_t)idx[b] * G3;
        ir = wr_[h] + bi0;
        iz = wr_[HH + h] + bi1;
        in_ = wr_[2 * HH + h] + bi2;
      }
      float gr = acc[0][r] + br, gz = acc[1][r] + bz, gn = acc[2][r] + bn;
      float rr = 1.f / (1.f + expf(-(ir + gr)));
      float zz = 1.f / (1.f + expf(-(iz + gz)));
      float ng = tanhf(in_ + rr * gn);
      float hold = h0r[(size_t)b * HH + h];
      h0w[(size_t)b * HH + h] = (1.f - zz) * ng + zz * hold;
    }
  } else {
    float bi0 = b_ih1[h], bi1 = b_ih1[HH + h], bi2 = b_ih1[2 * HH + h];
#pragma unroll
    for (int r = 0; r < 4; ++r) {
      int b = brow0 + r;
      const float* gsrc = gh1 + (size_t)b * G3 + hb * 48 + ci;
      float gr = gsrc[0], gz = gsrc[16], gn = gsrc[32];
      float rr = 1.f / (1.f + expf(-(acc[0][r] + bi0 + gr)));
      float zz = 1.f / (1.f + expf(-(acc[1][r] + bi1 + gz)));
      float ng = tanhf(acc[2][r] + bi2 + rr * gn);
      float hold = h1r[(size_t)b * HH + h];
      h1w[(size_t)b * HH + h] = (1.f - zz) * ng + zz * hold;
    }
  }
}

// ---------------- logits GEMM: logits = h1 @ W_out^T + b_out ----------------
// Block 64x64; wave w = m-group w covering 4 n-groups.
__global__ __launch_bounds__(256) void logits_kernel(
    const float* __restrict__ h1, const float* __restrict__ W_out,
    const float* __restrict__ b_out, float* __restrict__ logits) {
  __shared__ short Ahi[64 * 72], Alo[64 * 72];
  __shared__ short Whi[64 * 72], Wlo[64 * 72];
  const int tid = threadIdx.x;
  const int m0 = blockIdx.x * 64;
  const int n0 = blockIdx.y * 64;
  const int sr = tid >> 2, sc = (tid & 3) << 4;
  const int w = tid >> 6, ln = tid & 63, ci = ln & 15, qu = ln >> 4;

  f32x4 acc[4];
  acc[0] = (f32x4){0.f, 0.f, 0.f, 0.f};
  acc[1] = acc[0]; acc[2] = acc[0]; acc[3] = acc[0];

  const float* Abase = h1 + (size_t)(m0 + sr) * HH + sc;
  const float* Wbase = W_out + (size_t)(n0 + sr) * HH + sc;

  for (int kk = 0; kk < HH; kk += 64) {
    stage16(Abase + kk, &Ahi[sr * 72 + sc], &Alo[sr * 72 + sc]);
    stage16(Wbase + kk, &Whi[sr * 72 + sc], &Wlo[sr * 72 + sc]);
    __syncthreads();
#pragma unroll
    for (int s = 0; s < 2; ++s) {
      const int ko = s * 32 + qu * 8;
      bf16x8 ah = *(const bf16x8*)&Ahi[(w * 16 + ci) * 72 + ko];
      bf16x8 al = *(const bf16x8*)&Alo[(w * 16 + ci) * 72 + ko];
#pragma unroll
      for (int g = 0; g < 4; ++g) {
        bf16x8 bh = *(const bf16x8*)&Whi[(g * 16 + ci) * 72 + ko];
        bf16x8 bl = *(const bf16x8*)&Wlo[(g * 16 + ci) * 72 + ko];
        acc[g] = __builtin_amdgcn_mfma_f32_16x16x32_bf16(ah, bh, acc[g], 0, 0, 0);
        acc[g] = __builtin_amdgcn_mfma_f32_16x16x32_bf16(ah, bl, acc[g], 0, 0, 0);
        acc[g] = __builtin_amdgcn_mfma_f32_16x16x32_bf16(al, bh, acc[g], 0, 0, 0);
      }
    }
    __syncthreads();
  }
#pragma unroll
  for (int g = 0; g < 4; ++g) {
    int n = n0 + g * 16 + ci;
    float bo = b_out[n];
#pragma unroll
    for (int r = 0; r < 4; ++r) {
      int b = m0 + w * 16 + qu * 4 + r;
      logits[(size_t)b * NN + n] = acc[g][r] + bo;
    }
  }
}

// ---------------- sampler (bit-identical to round 1) ----------------
__global__ __launch_bounds__(256) void sample_kernel(
    const float* __restrict__ logits, uint32_t* __restrict__ avail,
    float* __restrict__ lp, int* __restrict__ idx,
    float* __restrict__ out_perm, float* __restrict__ out_lp, int t) {
  int b = blockIdx.x;
  int tid = threadIdx.x;

  uint32_t tp = (uint32_t)(t & 255);
  uint32_t a0, a1, b0, b1;
  threefry2x32(0u, 42u, 2u * tp, 2u * tp + 512u, a0, a1);
  threefry2x32(0u, 42u, 2u * tp + 1u, 2u * tp + 1u + 512u, b0, b1);
  uint32_t sk0 = (t < 256) ? a0 : a1;
  uint32_t sk1 = (t < 256) ? b0 : b1;

  __shared__ float rv[256];
  __shared__ int ri[256];
  __shared__ float rm[256];

  uint32_t bl = (uint32_t)(b & 127);
  float best_v = -1.0f / 0.0f;
  int best_i = 0;
  float mymax = -1.0f / 0.0f;
  float ml_[2];

#pragma unroll
  for (int j = 0; j < 2; ++j) {
    int c = tid + j * 256;
    uint32_t cnt = bl * 512u + (uint32_t)c;
    uint32_t r0, r1;
    threefry2x32(sk0, sk1, cnt, cnt + 65536u, r0, r1);
    uint32_t bits = (b < 128) ? r0 : r1;
    float u = __uint_as_float((bits >> 9) | 0x3f800000u) - 1.0f;
    if (u == 0.0f) u = 1.17549435e-38f;
    float g = -logf(-logf(u));
    float l = logits[(size_t)b * NN + c];
    bool av = (avail[b * 16 + (c >> 5)] >> (c & 31)) & 1u;
    float ml = av ? l : -1.0e9f;
    ml_[j] = ml;
    float v = g + ml;
    if (v > best_v || (v == best_v && c < best_i)) { best_v = v; best_i = c; }
    mymax = fmaxf(mymax, ml);
  }

  rv[tid] = best_v; ri[tid] = best_i; rm[tid] = mymax;
  __syncthreads();
  for (int s = 128; s > 0; s >>= 1) {
    if (tid < s) {
      float v2 = rv[tid + s]; int i2 = ri[tid + s];
      if (v2 > rv[tid] || (v2 == rv[tid] && i2 < ri[tid])) {
        rv[tid] = v2; ri[tid] = i2;
      }
      rm[tid] = fmaxf(rm[tid], rm[tid + s]);
    }
    __syncthreads();
  }
  float m = rm[0];
  int sel = ri[0];
  __syncthreads();
  rm[tid] = expf(ml_[0] - m) + expf(ml_[1] - m);
  __syncthreads();
  for (int s = 128; s > 0; s >>= 1) {
    if (tid < s) rm[tid] += rm[tid + s];
    __syncthreads();
  }
  if (tid == 0) {
    float ssum = rm[0];
    float lsel = logits[(size_t)b * NN + sel];
    float p = expf(lsel - m) / ssum;
    float lpn = lp[b] + logf(p + 1e-9f);
    lp[b] = lpn;
    out_lp[b] = lpn;
    idx[b] = sel;
    avail[b * 16 + (sel >> 5)] &= ~(1u << (sel & 31));
    out_perm[(size_t)b * NN * NN + (size_t)t * NN + sel] = 1.0f;
  }
}

// ---------------- host ----------------
extern "C" void kernel_launch(void* const* d_in, const int* in_sizes, int n_in,
                              void* d_out, int out_size, void* d_ws,
                              size_t ws_size, hipStream_t stream) {
  (void)in_sizes; (void)n_in; (void)ws_size;
  const float* W_ih0 = (const float*)d_in[1];
  const float* W_hh0 = (const float*)d_in[2];
  const float* b_ih0 = (const float*)d_in[3];
  const float* b_hh0 = (const float*)d_in[4];
  const float* W_ih1 = (const float*)d_in[5];
  const float* W_hh1 = (const float*)d_in[6];
  const float* b_ih1 = (const float*)d_in[7];
  const float* b_hh1 = (const float*)d_in[8];
  const float* W_out = (const float*)d_in[9];
  const float* b_out = (const float*)d_in[10];

  float* ws = (float*)d_ws;
  float* h0A = ws;                         // 131072
  float* h0B = ws + 131072;                // 131072
  float* h1A = ws + 262144;                // 131072
  float* h1B = ws + 393216;                // 131072
  float* gh1 = ws + 524288;                // 393216 (gate-interleaved)
  float* logits = ws + 917504;             // 131072
  float* W_ih0T = ws + 1048576;            // 786432
  float* ones_row = ws + 1835008;          // 1536
  float* lp = ws + 1836544;                // 256
  uint32_t* avail = (uint32_t*)(ws + 1836800);  // 4096 u32
  int* idx = (int*)(ws + 1840896);         // 256

  float* out = (float*)d_out;
  float* out_lp = out + (size_t)BB * NN * NN;

  hipMemsetAsync(d_out, 0, (size_t)out_size * sizeof(float), stream);
  init_state_kernel<<<2048, 256, 0, stream>>>(h0A, avail, lp, idx);
  ones_row_kernel<<<6, 256, 0, stream>>>(W_ih0, b_ih0, ones_row);
  transpose_kernel<<<dim3(16, 48), 256, 0, stream>>>(W_ih0, W_ih0T);

  float* h0r = h0A; float* h0w = h0B;
  float* h1r = h1A; float* h1w = h1B;
  for (int t = 0; t < NN; ++t) {
    // K1: mode0 (fused cell0 -> h0w) + mode1 (gh1) in one launch.
    fused_step_kernel<<<dim3(4, 32, 2), 256, 0, stream>>>(
        0, t, h0r, h0w, h1r, h1w, gh1, W_hh0, W_hh1, W_ih1, b_hh0, b_hh1,
        b_ih1, W_ih0T, b_ih0, ones_row, idx);
    // K2: mode2 (gi1 + fused cell1 -> h1w).
    fused_step_kernel<<<dim3(4, 32, 1), 256, 0, stream>>>(
        2, t, h0r, h0w, h1r, h1w, gh1, W_hh0, W_hh1, W_ih1, b_hh0, b_hh1,
        b_ih1, W_ih0T, b_ih0, ones_row, idx);
    // K3: logits = h1w @ W_out^T + b_out
    logits_kernel<<<dim3(4, 8), 256, 0, stream>>>(h1w, W_out, b_out, logits);
    // K4: threefry-exact gumbel-argmax sampler
    sample_kernel<<<256, 256, 0, stream>>>(logits, avail, lp, idx, out, out_lp,
                                           t);
    float* tmp = h0r; h0r = h0w; h0w = tmp;
    tmp = h1r; h1r = h1w; h1w = tmp;
  }
}